// Round 2
// baseline (86.652 us; speedup 1.0000x reference)
//
#include <hip/hip_runtime.h>

// RGBuvHistBlock: soft histogram (Gaussian kernel, sigma=0.02) over 64 bins in [-1,1].
// x: [8,3,256,256] f32 in [0,1] -> xs = 2x-1; hist[n,c,b] = sum_px exp(-(xs-bin_b)^2/(2*sigma^2))
// normalized by per-channel sum + 1e-8. Output [8,3,64] f32.

#define NCH   24        // 8*3 channels
#define HW    65536     // 256*256
#define BPC   32        // blocks per channel
#define NBIN  64

// C = -1/(2*sigma^2) * log2(e) = -1250 * 1.4426950408889634
#define EXP_C (-1803.3688011112042f)

__global__ __launch_bounds__(256) void hist_accum(const float* __restrict__ x,
                                                  float* __restrict__ part) {
    const int ch  = blockIdx.x >> 5;   // / BPC
    const int sub = blockIdx.x & 31;   // % BPC
    // each block: 2048 pixels = 512 float4; 256 threads x 2 iters
    const float4* xv = reinterpret_cast<const float4*>(x) + ch * (HW / 4) + sub * 512;

    float acc[NBIN];
#pragma unroll
    for (int j = 0; j < NBIN; ++j) acc[j] = 0.0f;

#pragma unroll
    for (int it = 0; it < 2; ++it) {
        float4 v = xv[it * 256 + threadIdx.x];
        const float p0 = 2.0f * v.x - 1.0f;
        const float p1 = 2.0f * v.y - 1.0f;
        const float p2 = 2.0f * v.z - 1.0f;
        const float p3 = 2.0f * v.w - 1.0f;
#pragma unroll
        for (int j = 0; j < NBIN; ++j) {
            const float b = (float)(-1.0 + j * (2.0 / 63.0));  // compile-time literal
            float d0 = p0 - b, d1 = p1 - b, d2 = p2 - b, d3 = p3 - b;
            float w0 = __builtin_amdgcn_exp2f(d0 * d0 * EXP_C);
            float w1 = __builtin_amdgcn_exp2f(d1 * d1 * EXP_C);
            float w2 = __builtin_amdgcn_exp2f(d2 * d2 * EXP_C);
            float w3 = __builtin_amdgcn_exp2f(d3 * d3 * EXP_C);
            acc[j] += (w0 + w1) + (w2 + w3);
        }
    }

    __shared__ float lh[NBIN];
    const int tid = threadIdx.x;
    if (tid < NBIN) lh[tid] = 0.0f;
    __syncthreads();

    const int lane = tid & 63;
#pragma unroll
    for (int j = 0; j < NBIN; ++j) {
        float v = acc[j];
        v += __shfl_xor(v, 32);
        v += __shfl_xor(v, 16);
        v += __shfl_xor(v, 8);
        v += __shfl_xor(v, 4);
        v += __shfl_xor(v, 2);
        v += __shfl_xor(v, 1);
        if (lane == 0) atomicAdd(&lh[j], v);  // 4 waves -> <=4-way conflict
    }
    __syncthreads();
    if (tid < NBIN) atomicAdd(&part[ch * NBIN + tid], lh[tid]);
}

__global__ __launch_bounds__(64) void hist_norm(const float* __restrict__ part,
                                                float* __restrict__ out) {
    const int ch = blockIdx.x;
    const int t  = threadIdx.x;  // 0..63, one wave
    float h = part[ch * NBIN + t];
    float s = h;
    s += __shfl_xor(s, 32);
    s += __shfl_xor(s, 16);
    s += __shfl_xor(s, 8);
    s += __shfl_xor(s, 4);
    s += __shfl_xor(s, 2);
    s += __shfl_xor(s, 1);
    out[ch * NBIN + t] = h / (s + 1e-8f);
}

extern "C" void kernel_launch(void* const* d_in, const int* in_sizes, int n_in,
                              void* d_out, int out_size, void* d_ws, size_t ws_size,
                              hipStream_t stream) {
    const float* x = (const float*)d_in[0];
    float* part = (float*)d_ws;

    hipMemsetAsync(d_ws, 0, NCH * NBIN * sizeof(float), stream);
    hist_accum<<<NCH * BPC, 256, 0, stream>>>(x, part);
    hist_norm<<<NCH, NBIN, 0, stream>>>(part, (float*)d_out);
}